// Round 13
// baseline (75.256 us; speedup 1.0000x reference)
//
#include <hip/hip_runtime.h>
#include <hip/hip_bf16.h>

#ifndef __has_builtin
#define __has_builtin(x) 0
#endif

__device__ __forceinline__ float fast_exp2(float x) {
#if __has_builtin(__builtin_amdgcn_exp2f)
  return __builtin_amdgcn_exp2f(x);
#else
  return __exp2f(x);
#endif
}
__device__ __forceinline__ float fast_rcp(float x) {
#if __has_builtin(__builtin_amdgcn_rcpf)
  return __builtin_amdgcn_rcpf(x);
#else
  return 1.0f / x;
#endif
}

#define B_   16
#define NQ_  256
#define NK_  256
#define D_   256
#define QT   4
#define TANH_SCALE 2.8853900817779268f
#define NEG2LOG2E  (-2.8853900817779268f)   // p = exp(-2*acc) = exp2(acc*this)

// ---------------- projection GEMM: 32x64 tiles, grid 1024 -------------------
// proj was the only attributable fat left: 64x64 tiles = 512 blocks = 2
// blocks/CU = 2 waves/SIMD (vs 537M-MAC issue floor ~7us, measured ~15-17us).
// 32x64 -> 1024 blocks = 4 blocks/CU = 16 waves/CU. Scalar fma (pk_fma
// regressed 4x in R5). A stored [m][k] (reads across k, 2-way conflicts max).
// z=0: Eq = exp2(TANH_SCALE*(queries@Wq + b1));  z=1: Ek = exp2(...keys@Wk).
__global__ __launch_bounds__(256) void proj_kernel(
    const float* __restrict__ queries, const float* __restrict__ keys,
    const float* __restrict__ Wq, const float* __restrict__ Wk,
    const float* __restrict__ b1,
    float* __restrict__ eqs, float* __restrict__ eks)
{
  const int z = blockIdx.z;
  const float* __restrict__ X = z ? keys : queries;
  const float* __restrict__ W = z ? Wk : Wq;
  float* __restrict__ O = z ? eks : eqs;

  const int m0 = blockIdx.x * 32;
  const int n0 = blockIdx.y * 64;
  const int t  = threadIdx.x;
  const int tx = t & 15, ty = t >> 4;   // tx: 4-col group, ty: 2-row group

  __shared__ float As[32][68];   // [m][k], padded
  __shared__ float Bs[64][68];   // [k][n]

  float acc[2][4] = {};

  for (int kt = 0; kt < 4; ++kt) {
    const int k0 = kt * 64;
    #pragma unroll
    for (int i = 0; i < 2; ++i) {          // A tile: 32x64 = 512 float4
      int f = t + 256 * i;
      int row = f >> 4;
      int kc  = (f & 15) << 2;
      *(float4*)&As[row][kc] = *(const float4*)&X[(size_t)(m0 + row) * D_ + (k0 + kc)];
    }
    #pragma unroll
    for (int i = 0; i < 4; ++i) {          // B tile: 64x64
      int f = t + 256 * i;
      int kr = f >> 4;
      int nc = (f & 15) << 2;
      *(float4*)&Bs[kr][nc] = *(const float4*)&W[(size_t)(k0 + kr) * D_ + (n0 + nc)];
    }
    __syncthreads();
    #pragma unroll 4
    for (int k4 = 0; k4 < 16; ++k4) {      // 4 k's per iter
      const int kk = k4 << 2;
      float4 a0 = *(const float4*)&As[(ty << 1) + 0][kk];
      float4 a1 = *(const float4*)&As[(ty << 1) + 1][kk];
      float4 b0 = *(const float4*)&Bs[kk + 0][tx << 2];
      float4 b1v = *(const float4*)&Bs[kk + 1][tx << 2];
      float4 b2 = *(const float4*)&Bs[kk + 2][tx << 2];
      float4 b3 = *(const float4*)&Bs[kk + 3][tx << 2];
      float A[2][4] = {{a0.x,a0.y,a0.z,a0.w},{a1.x,a1.y,a1.z,a1.w}};
      float Bv[4][4] = {{b0.x,b0.y,b0.z,b0.w},{b1v.x,b1v.y,b1v.z,b1v.w},
                        {b2.x,b2.y,b2.z,b2.w},{b3.x,b3.y,b3.z,b3.w}};
      #pragma unroll
      for (int kkk = 0; kkk < 4; ++kkk)
        #pragma unroll
        for (int i = 0; i < 2; ++i)
          #pragma unroll
          for (int j = 0; j < 4; ++j)
            acc[i][j] = fmaf(A[i][kkk], Bv[kkk][j], acc[i][j]);
    }
    __syncthreads();
  }

  float bias[4] = {0.f, 0.f, 0.f, 0.f};
  if (z == 0) {
    #pragma unroll
    for (int j = 0; j < 4; ++j) bias[j] = b1[n0 + (tx << 2) + j];
  }
  #pragma unroll
  for (int i = 0; i < 2; ++i) {
    float4 o4;
    o4.x = fast_exp2(TANH_SCALE * (acc[i][0] + bias[0]));
    o4.y = fast_exp2(TANH_SCALE * (acc[i][1] + bias[1]));
    o4.z = fast_exp2(TANH_SCALE * (acc[i][2] + bias[2]));
    o4.w = fast_exp2(TANH_SCALE * (acc[i][3] + bias[3]));
    *(float4*)&O[(size_t)(m0 + (ty << 1) + i) * D_ + n0 + (tx << 2)] = o4;
  }
}

// ---------------- fused logits + softmax + PV (R10 verbatim + unroll 8) ----
// Attn is pinned at 50+-3us across six falsified structural theories
// (occupancy R7, operand delivery R3/R5, LDS pipe R9, issue count R10,
// coalescing R11, block granularity R12) — practical plateau. Only remaining
// free knob: deeper unroll (8) for more loads in flight per group.
// Quad-rcp; no-max softmax (|logit| <= 2*sum|w2| ~ 26, verified R4-R12);
// eq/w2 block-uniform -> s_load; b = wgid&15 pins 2 batches per XCD.
__global__ __launch_bounds__(256, 4) void attn_kernel(
    const float* __restrict__ eqs, const float* __restrict__ eks,
    const float* __restrict__ values, const float* __restrict__ w2,
    float* __restrict__ out)
{
  const int wgid = blockIdx.x;
  const int b  = wgid & 15;
  const int q0 = (wgid >> 4) * QT;
  const int t  = threadIdx.x;
  const int lane = t & 63, wave = t >> 6;

  __shared__ float pvred[4][QT][D_];          // 16KB
  __shared__ float redB[4][QT];

  const float* __restrict__ ekrow = eks + ((size_t)(b * NK_) + t) * D_;
  const float* __restrict__ equni = eqs + ((size_t)(b * NQ_) + q0) * D_;  // uniform

  float acc[QT] = {};
  #pragma unroll 8
  for (int d4 = 0; d4 < D_ / 4; ++d4) {
    const int off = d4 << 2;
    float4 ekv = *(const float4*)&ekrow[off];
    float4 wv  = *(const float4*)&w2[off];               // uniform -> s_load
    float e[4] = {ekv.x, ekv.y, ekv.z, ekv.w};
    float w[4] = {wv.x, wv.y, wv.z, wv.w};
    #pragma unroll
    for (int qi = 0; qi < QT; ++qi) {
      float4 eqv = *(const float4*)&equni[(size_t)qi * D_ + off];  // uniform
      float t0 = fmaf(eqv.x, e[0], 1.0f);
      float t1 = fmaf(eqv.y, e[1], 1.0f);
      float t2 = fmaf(eqv.z, e[2], 1.0f);
      float t3 = fmaf(eqv.w, e[3], 1.0f);
      float p01 = t0 * t1;
      float p23 = t2 * t3;
      float n01 = fmaf(w[1], t0, w[0] * t1);
      float n23 = fmaf(w[3], t2, w[2] * t3);
      float num = fmaf(n23, p01, n01 * p23);
      float r   = fast_rcp(p01 * p23);
      acc[qi] = fmaf(num, r, acc[qi]);
    }
  }

  // ---- no-max softmax: p = exp2(-2*log2e*acc), block-wide denominator ----
  float p[QT];
  #pragma unroll
  for (int qi = 0; qi < QT; ++qi)
    p[qi] = fast_exp2(NEG2LOG2E * acc[qi]);
  #pragma unroll
  for (int qi = 0; qi < QT; ++qi) {
    float v = p[qi];
    #pragma unroll
    for (int off = 32; off; off >>= 1) v += __shfl_xor(v, off, 64);
    if (lane == 0) redB[wave][qi] = v;
  }
  __syncthreads();
  float pl[QT];
  #pragma unroll
  for (int qi = 0; qi < QT; ++qi) {
    float inv = fast_rcp(redB[0][qi] + redB[1][qi] + redB[2][qi] + redB[3][qi]);
    pl[qi] = p[qi] * inv;   // normalized weight for this thread's key
  }

  // ---- PV: wave-local over its 64 keys, p broadcast via readlane ----
  float ctx[QT][4] = {};
  const float* __restrict__ vbase =
      values + ((size_t)(b * NK_) + (wave << 6)) * D_ + (lane << 2);
  #pragma unroll 4
  for (int kl = 0; kl < 64; ++kl) {
    float4 vv = *(const float4*)&vbase[(size_t)kl * D_];
    float vz[4] = {vv.x, vv.y, vv.z, vv.w};
    #pragma unroll
    for (int qi = 0; qi < QT; ++qi) {
      float pk = __int_as_float(
          __builtin_amdgcn_readlane(__float_as_int(pl[qi]), kl));
      #pragma unroll
      for (int j = 0; j < 4; ++j)
        ctx[qi][j] = fmaf(pk, vz[j], ctx[qi][j]);
    }
  }

  // ---- combine 4 waves' partials via LDS ----
  #pragma unroll
  for (int qi = 0; qi < QT; ++qi)
    *(float4*)&pvred[wave][qi][lane << 2] =
        make_float4(ctx[qi][0], ctx[qi][1], ctx[qi][2], ctx[qi][3]);
  __syncthreads();
  #pragma unroll
  for (int qi = 0; qi < QT; ++qi) {
    float o = pvred[0][qi][t] + pvred[1][qi][t] +
              pvred[2][qi][t] + pvred[3][qi][t];
    out[((size_t)(b * NQ_) + q0 + qi) * D_ + t] = o;
  }
}

extern "C" void kernel_launch(void* const* d_in, const int* in_sizes, int n_in,
                              void* d_out, int out_size, void* d_ws, size_t ws_size,
                              hipStream_t stream)
{
  const float* keys    = (const float*)d_in[0];
  const float* queries = (const float*)d_in[1];
  const float* values  = (const float*)d_in[2];
  const float* Wk      = (const float*)d_in[3];
  const float* Wq      = (const float*)d_in[4];
  const float* b1      = (const float*)d_in[5];
  const float* w2      = (const float*)d_in[6];
  // d_in[7] = b2: dropped (softmax shift-invariance)

  float* eqs = (float*)d_ws;                       // [4096,256] f32, 4 MB
  float* eks = eqs + (size_t)B_ * NQ_ * D_;        // [4096,256] f32, 4 MB
  float* out = (float*)d_out;

  dim3 pgrid(B_ * NQ_ / 32, D_ / 64, 2);           // 128 x 4 x 2 = 1024 blocks
  proj_kernel<<<pgrid, 256, 0, stream>>>(queries, keys, Wq, Wk, b1, eqs, eks);

  attn_kernel<<<dim3(B_ * NQ_ / QT), 256, 0, stream>>>(eqs, eks, values, w2, out);
}

// Round 14
// 68.032 us; speedup vs baseline: 1.1062x; 1.1062x over previous
//
#include <hip/hip_runtime.h>
#include <hip/hip_bf16.h>

#ifndef __has_builtin
#define __has_builtin(x) 0
#endif

__device__ __forceinline__ float fast_exp2(float x) {
#if __has_builtin(__builtin_amdgcn_exp2f)
  return __builtin_amdgcn_exp2f(x);
#else
  return __exp2f(x);
#endif
}
__device__ __forceinline__ float fast_rcp(float x) {
#if __has_builtin(__builtin_amdgcn_rcpf)
  return __builtin_amdgcn_rcpf(x);
#else
  return 1.0f / x;
#endif
}

#define B_   16
#define NQ_  256
#define NK_  256
#define D_   256
#define QT   4
#define TANH_SCALE 2.8853900817779268f
#define NEG2LOG2E  (-2.8853900817779268f)   // p = exp(-2*acc) = exp2(acc*this)

// ---------------- projection GEMM (R10 config — best measured total) --------
// z=0: Eq = exp2(TANH_SCALE*(queries@Wq + b1));  z=1: Ek = exp2(...keys@Wk).
// A stored [m][k]; inner loop reads A as float4 across k (8 b128/4 k-iters).
__global__ __launch_bounds__(256) void proj_kernel(
    const float* __restrict__ queries, const float* __restrict__ keys,
    const float* __restrict__ Wq, const float* __restrict__ Wk,
    const float* __restrict__ b1,
    float* __restrict__ eqs, float* __restrict__ eks)
{
  const int z = blockIdx.z;
  const float* __restrict__ X = z ? keys : queries;
  const float* __restrict__ W = z ? Wk : Wq;
  float* __restrict__ O = z ? eks : eqs;

  const int m0 = blockIdx.x * 64;
  const int n0 = blockIdx.y * 64;
  const int t  = threadIdx.x;
  const int tx = t & 15, ty = t >> 4;

  __shared__ float As[64][68];   // [m][k], padded
  __shared__ float Bs[64][68];   // [k][n]

  float acc[4][4] = {};

  for (int kt = 0; kt < 4; ++kt) {
    const int k0 = kt * 64;
    #pragma unroll
    for (int i = 0; i < 4; ++i) {          // A tile, direct copy
      int f = t + 256 * i;
      int row = f >> 4;
      int kc  = (f & 15) << 2;
      *(float4*)&As[row][kc] = *(const float4*)&X[(size_t)(m0 + row) * D_ + (k0 + kc)];
    }
    #pragma unroll
    for (int i = 0; i < 4; ++i) {          // B tile
      int f = t + 256 * i;
      int kr = f >> 4;
      int nc = (f & 15) << 2;
      *(float4*)&Bs[kr][nc] = *(const float4*)&W[(size_t)(k0 + kr) * D_ + (n0 + nc)];
    }
    __syncthreads();
    #pragma unroll 4
    for (int k4 = 0; k4 < 16; ++k4) {      // 4 k's per iter
      const int kk = k4 << 2;
      float4 a0 = *(const float4*)&As[(ty << 2) + 0][kk];
      float4 a1 = *(const float4*)&As[(ty << 2) + 1][kk];
      float4 a2 = *(const float4*)&As[(ty << 2) + 2][kk];
      float4 a3 = *(const float4*)&As[(ty << 2) + 3][kk];
      float4 b0 = *(const float4*)&Bs[kk + 0][tx << 2];
      float4 b1v = *(const float4*)&Bs[kk + 1][tx << 2];
      float4 b2 = *(const float4*)&Bs[kk + 2][tx << 2];
      float4 b3 = *(const float4*)&Bs[kk + 3][tx << 2];
      float A[4][4] = {{a0.x,a0.y,a0.z,a0.w},{a1.x,a1.y,a1.z,a1.w},
                       {a2.x,a2.y,a2.z,a2.w},{a3.x,a3.y,a3.z,a3.w}};
      float Bv[4][4] = {{b0.x,b0.y,b0.z,b0.w},{b1v.x,b1v.y,b1v.z,b1v.w},
                        {b2.x,b2.y,b2.z,b2.w},{b3.x,b3.y,b3.z,b3.w}};
      #pragma unroll
      for (int kkk = 0; kkk < 4; ++kkk)
        #pragma unroll
        for (int i = 0; i < 4; ++i)
          #pragma unroll
          for (int j = 0; j < 4; ++j)
            acc[i][j] = fmaf(A[i][kkk], Bv[kkk][j], acc[i][j]);
    }
    __syncthreads();
  }

  float bias[4] = {0.f, 0.f, 0.f, 0.f};
  if (z == 0) {
    #pragma unroll
    for (int j = 0; j < 4; ++j) bias[j] = b1[n0 + (tx << 2) + j];
  }
  #pragma unroll
  for (int i = 0; i < 4; ++i) {
    float4 o4;
    o4.x = fast_exp2(TANH_SCALE * (acc[i][0] + bias[0]));
    o4.y = fast_exp2(TANH_SCALE * (acc[i][1] + bias[1]));
    o4.z = fast_exp2(TANH_SCALE * (acc[i][2] + bias[2]));
    o4.w = fast_exp2(TANH_SCALE * (acc[i][3] + bias[3]));
    *(float4*)&O[(size_t)(m0 + (ty << 2) + i) * D_ + n0 + (tx << 2)] = o4;
  }
}

// ---------------- fused logits + softmax + PV (R10 verbatim) ---------------
// Attn pinned at 50+-3us across eight falsified/exhausted axes (occupancy R7,
// operand delivery R3/R5/R9, LDS pipe R9, issue count R10, coalescing R11,
// block granularity R12, unroll depth R13, tile shape R13) — practical
// plateau for this toolchain. Quad-rcp (1 rcp per qi*d4); no-max softmax
// (|logit| <= 2*sum|w2| ~ 26, verified R4-R13); eq/w2 block-uniform ->
// s_load; b = wgid&15 pins 2 batches per XCD.
__global__ __launch_bounds__(256, 4) void attn_kernel(
    const float* __restrict__ eqs, const float* __restrict__ eks,
    const float* __restrict__ values, const float* __restrict__ w2,
    float* __restrict__ out)
{
  const int wgid = blockIdx.x;
  const int b  = wgid & 15;
  const int q0 = (wgid >> 4) * QT;
  const int t  = threadIdx.x;
  const int lane = t & 63, wave = t >> 6;

  __shared__ float pvred[4][QT][D_];          // 16KB
  __shared__ float redB[4][QT];

  const float* __restrict__ ekrow = eks + ((size_t)(b * NK_) + t) * D_;
  const float* __restrict__ equni = eqs + ((size_t)(b * NQ_) + q0) * D_;  // uniform

  float acc[QT] = {};
  #pragma unroll 4
  for (int d4 = 0; d4 < D_ / 4; ++d4) {
    const int off = d4 << 2;
    float4 ekv = *(const float4*)&ekrow[off];
    float4 wv  = *(const float4*)&w2[off];               // uniform -> s_load
    float e[4] = {ekv.x, ekv.y, ekv.z, ekv.w};
    float w[4] = {wv.x, wv.y, wv.z, wv.w};
    #pragma unroll
    for (int qi = 0; qi < QT; ++qi) {
      float4 eqv = *(const float4*)&equni[(size_t)qi * D_ + off];  // uniform
      float t0 = fmaf(eqv.x, e[0], 1.0f);
      float t1 = fmaf(eqv.y, e[1], 1.0f);
      float t2 = fmaf(eqv.z, e[2], 1.0f);
      float t3 = fmaf(eqv.w, e[3], 1.0f);
      float p01 = t0 * t1;
      float p23 = t2 * t3;
      float n01 = fmaf(w[1], t0, w[0] * t1);
      float n23 = fmaf(w[3], t2, w[2] * t3);
      float num = fmaf(n23, p01, n01 * p23);
      float r   = fast_rcp(p01 * p23);
      acc[qi] = fmaf(num, r, acc[qi]);
    }
  }

  // ---- no-max softmax: p = exp2(-2*log2e*acc), block-wide denominator ----
  float p[QT];
  #pragma unroll
  for (int qi = 0; qi < QT; ++qi)
    p[qi] = fast_exp2(NEG2LOG2E * acc[qi]);
  #pragma unroll
  for (int qi = 0; qi < QT; ++qi) {
    float v = p[qi];
    #pragma unroll
    for (int off = 32; off; off >>= 1) v += __shfl_xor(v, off, 64);
    if (lane == 0) redB[wave][qi] = v;
  }
  __syncthreads();
  float pl[QT];
  #pragma unroll
  for (int qi = 0; qi < QT; ++qi) {
    float inv = fast_rcp(redB[0][qi] + redB[1][qi] + redB[2][qi] + redB[3][qi]);
    pl[qi] = p[qi] * inv;   // normalized weight for this thread's key
  }

  // ---- PV: wave-local over its 64 keys, p broadcast via readlane ----
  float ctx[QT][4] = {};
  const float* __restrict__ vbase =
      values + ((size_t)(b * NK_) + (wave << 6)) * D_ + (lane << 2);
  #pragma unroll 4
  for (int kl = 0; kl < 64; ++kl) {
    float4 vv = *(const float4*)&vbase[(size_t)kl * D_];
    float vz[4] = {vv.x, vv.y, vv.z, vv.w};
    #pragma unroll
    for (int qi = 0; qi < QT; ++qi) {
      float pk = __int_as_float(
          __builtin_amdgcn_readlane(__float_as_int(pl[qi]), kl));
      #pragma unroll
      for (int j = 0; j < 4; ++j)
        ctx[qi][j] = fmaf(pk, vz[j], ctx[qi][j]);
    }
  }

  // ---- combine 4 waves' partials via LDS ----
  #pragma unroll
  for (int qi = 0; qi < QT; ++qi)
    *(float4*)&pvred[wave][qi][lane << 2] =
        make_float4(ctx[qi][0], ctx[qi][1], ctx[qi][2], ctx[qi][3]);
  __syncthreads();
  #pragma unroll
  for (int qi = 0; qi < QT; ++qi) {
    float o = pvred[0][qi][t] + pvred[1][qi][t] +
              pvred[2][qi][t] + pvred[3][qi][t];
    out[((size_t)(b * NQ_) + q0 + qi) * D_ + t] = o;
  }
}

extern "C" void kernel_launch(void* const* d_in, const int* in_sizes, int n_in,
                              void* d_out, int out_size, void* d_ws, size_t ws_size,
                              hipStream_t stream)
{
  const float* keys    = (const float*)d_in[0];
  const float* queries = (const float*)d_in[1];
  const float* values  = (const float*)d_in[2];
  const float* Wk      = (const float*)d_in[3];
  const float* Wq      = (const float*)d_in[4];
  const float* b1      = (const float*)d_in[5];
  const float* w2      = (const float*)d_in[6];
  // d_in[7] = b2: dropped (softmax shift-invariance)

  float* eqs = (float*)d_ws;                       // [4096,256] f32, 4 MB
  float* eks = eqs + (size_t)B_ * NQ_ * D_;        // [4096,256] f32, 4 MB
  float* out = (float*)d_out;

  dim3 pgrid(B_ * NQ_ / 64, D_ / 64, 2);           // 64 x 4 x 2 = 512 blocks
  proj_kernel<<<pgrid, 256, 0, stream>>>(queries, keys, Wq, Wk, b1, eqs, eks);

  attn_kernel<<<dim3(B_ * NQ_ / QT), 256, 0, stream>>>(eqs, eks, values, w2, out);
}